// Round 4
// baseline (163380.298 us; speedup 1.0000x reference)
//
#include <hip/hip_runtime.h>
#include <hip/hip_bf16.h>

typedef unsigned short u16;
typedef unsigned int   u32;
typedef float  f32x4  __attribute__((ext_vector_type(4)));
typedef __bf16 bf16x8 __attribute__((ext_vector_type(8)));
typedef unsigned short u16x4 __attribute__((ext_vector_type(4)));
typedef unsigned short u16x8 __attribute__((ext_vector_type(8)));

__device__ __forceinline__ u16 rne_bf16(float f) {
  u32 u = __builtin_bit_cast(u32, f);
  return (u16)((u + 0x7fffu + ((u >> 16) & 1u)) >> 16);
}

// ---------------------------------------------------------------------------
// table-driven fp32 -> bf16 (round-3 version, under test)
// ---------------------------------------------------------------------------
struct CvtTable {
  const float* src[16];
  u16*         dst[16];
  int blk_start[16];
  int nbuf;
};

__global__ __launch_bounds__(256) void cvt_f32_to_bf16(CvtTable t) {
  int blk = blockIdx.x;
  int b = 0;
#pragma unroll
  for (int i = 1; i < 16; ++i)
    if (i < t.nbuf && blk >= t.blk_start[i]) b = i;
  long off4 = (long)(blk - t.blk_start[b]) * 256 + threadIdx.x;
  f32x4 v = ((const f32x4*)t.src[b])[off4];
  u16x4 o;
#pragma unroll
  for (int j = 0; j < 4; ++j) o[j] = rne_bf16(v[j]);
  ((u16x4*)t.dst[b])[off4] = o;
}

// dead-simple scalar fp32 -> bf16 (trusted reference path)
__global__ __launch_bounds__(256) void cvt_scalar(const float* __restrict__ s,
                                                  u16* __restrict__ d, long n) {
  long i = (long)blockIdx.x * 256 + threadIdx.x;
  if (i < n) d[i] = rne_bf16(s[i]);
}

// ---------------------------------------------------------------------------
// Grouped bf16 MFMA GEMM — identical to round 2/3 (under test)
// ---------------------------------------------------------------------------
struct GemmTable {
  const u16* A[8];
  const u16* B[8];
  float*     C[8];
  int N[8], K[8];
  int tstart[8];
  int ngroups;
  int total;
};

__global__ __launch_bounds__(256) void gemm_bf16_grouped(GemmTable t) {
  int nwg  = t.total;
  int orig = blockIdx.x;
  int q = nwg >> 3, r = nwg & 7;
  int xcd = orig & 7, idx = orig >> 3;
  int wgid = (xcd < r ? xcd * (q + 1) : r * (q + 1) + (xcd - r) * q) + idx;

  int g = 0;
#pragma unroll
  for (int i = 1; i < 8; ++i)
    if (i < t.ngroups && wgid >= t.tstart[i]) g = i;

  const int K = t.K[g];
  const int N = t.N[g];
  int local = wgid - t.tstart[g];
  int ntn = N >> 7;
  int bm = local / ntn;
  int bn = local - bm * ntn;

  __shared__ u16 lsA[128 * 32];
  __shared__ u16 lsB[128 * 32];

  const int tid  = threadIdx.x;
  const int wid  = tid >> 6;
  const int lane = tid & 63;
  const int wr = wid >> 1, wc = wid & 1;

  const int e0 = ((wid * 2 + 0) * 64 + lane) * 8;
  const int e1 = ((wid * 2 + 1) * 64 + lane) * 8;
  const int r0 = e0 >> 5, c0 = e0 & 31;
  const int r1 = e1 >> 5, c1 = e1 & 31;

  const u16* a0 = t.A[g] + (size_t)(bm * 128 + r0) * K + c0;
  const u16* a1 = t.A[g] + (size_t)(bm * 128 + r1) * K + c1;
  const u16* b0 = t.B[g] + (size_t)(bn * 128 + r0) * K + c0;
  const u16* b1 = t.B[g] + (size_t)(bn * 128 + r1) * K + c1;

  f32x4 acc[4][4];
#pragma unroll
  for (int i = 0; i < 4; ++i)
#pragma unroll
    for (int j = 0; j < 4; ++j)
      acc[i][j] = (f32x4){0.f, 0.f, 0.f, 0.f};

  const int arow = wr * 64 + (lane & 15);
  const int brow = wc * 64 + (lane & 15);
  const int kcol = (lane >> 4) * 8;

  u16x8 rA0 = *(const u16x8*)(a0);
  u16x8 rA1 = *(const u16x8*)(a1);
  u16x8 rB0 = *(const u16x8*)(b0);
  u16x8 rB1 = *(const u16x8*)(b1);

  for (int k0 = 0; k0 < K; k0 += 32) {
    *(u16x8*)&lsA[e0] = rA0;
    *(u16x8*)&lsA[e1] = rA1;
    *(u16x8*)&lsB[e0] = rB0;
    *(u16x8*)&lsB[e1] = rB1;
    __syncthreads();

    if (k0 + 32 < K) {
      rA0 = *(const u16x8*)(a0 + k0 + 32);
      rA1 = *(const u16x8*)(a1 + k0 + 32);
      rB0 = *(const u16x8*)(b0 + k0 + 32);
      rB1 = *(const u16x8*)(b1 + k0 + 32);
    }

    bf16x8 af[4], bfr[4];
#pragma unroll
    for (int i = 0; i < 4; ++i)
      af[i] = *(const bf16x8*)&lsA[(arow + i * 16) * 32 + kcol];
#pragma unroll
    for (int j = 0; j < 4; ++j)
      bfr[j] = *(const bf16x8*)&lsB[(brow + j * 16) * 32 + kcol];

#pragma unroll
    for (int i = 0; i < 4; ++i)
#pragma unroll
      for (int j = 0; j < 4; ++j)
        acc[i][j] = __builtin_amdgcn_mfma_f32_16x16x32_bf16(af[i], bfr[j], acc[i][j], 0, 0, 0);
    __syncthreads();
  }

  float* Cp = t.C[g];
  const int crow = bm * 128 + wr * 64 + (lane >> 4) * 4;
  const int ccol = bn * 128 + wc * 64 + (lane & 15);
#pragma unroll
  for (int i = 0; i < 4; ++i)
#pragma unroll
    for (int j = 0; j < 4; ++j)
#pragma unroll
      for (int rr = 0; rr < 4; ++rr)
        Cp[(size_t)(crow + i * 16 + rr) * N + ccol + j * 16] = acc[i][j][rr];
}

// ---------------------------------------------------------------------------
// Diagnostic naive kernels
// ---------------------------------------------------------------------------
__global__ __launch_bounds__(256) void naive_gemm_f32(const float* __restrict__ X,
                                                      const float* __restrict__ W,
                                                      float* __restrict__ C,
                                                      long MN, int N, int K) {
  long i = (long)blockIdx.x * 256 + threadIdx.x;
  if (i >= MN) return;
  int m = (int)(i / N), n = (int)(i - (long)m * N);
  const float* x = X + (size_t)m * K;
  const float* w = W + (size_t)n * K;
  float s = 0.f;
  for (int k = 0; k < K; ++k) s += x[k] * w[k];
  C[i] = s;
}

__global__ __launch_bounds__(256) void naive_gemm_bf16(const u16* __restrict__ X,
                                                       const u16* __restrict__ W,
                                                       float* __restrict__ C,
                                                       long MN, int N, int K) {
  long i = (long)blockIdx.x * 256 + threadIdx.x;
  if (i >= MN) return;
  int m = (int)(i / N), n = (int)(i - (long)m * N);
  const u16* x = X + (size_t)m * K;
  const u16* w = W + (size_t)n * K;
  float s = 0.f;
  for (int k = 0; k < K; ++k) {
    float a = __builtin_bit_cast(float, (u32)x[k] << 16);
    float b = __builtin_bit_cast(float, (u32)w[k] << 16);
    s += a * b;
  }
  C[i] = s;
}

// on-the-fly bf16 rounding, no workspace involved at all
__global__ __launch_bounds__(256) void naive_gemm_rt_bf16(const float* __restrict__ X,
                                                          const float* __restrict__ W,
                                                          float* __restrict__ C,
                                                          long MN, int N, int K) {
  long i = (long)blockIdx.x * 256 + threadIdx.x;
  if (i >= MN) return;
  int m = (int)(i / N), n = (int)(i - (long)m * N);
  const float* x = X + (size_t)m * K;
  const float* w = W + (size_t)n * K;
  float s = 0.f;
  for (int k = 0; k < K; ++k) {
    float a = __builtin_bit_cast(float, (u32)rne_bf16(x[k]) << 16);
    float b = __builtin_bit_cast(float, (u32)rne_bf16(w[k]) << 16);
    s += a * b;
  }
  C[i] = s;
}

// ---------------------------------------------------------------------------
extern "C" void kernel_launch(void* const* d_in, const int* in_sizes, int n_in,
                              void* d_out, int out_size, void* d_ws, size_t ws_size,
                              hipStream_t stream) {
  static const int Ms[8] = {4096, 8192, 2048, 16384, 1024, 4096, 2048, 8192};
  static const int Ks[8] = {1024, 2048,  512,  1024, 2048,  768, 3072, 1024};
  static const int Ns[8] = {2048, 1024, 2048,  1024, 2048, 3072,  768, 4096};
  static const int xs_sz[8] = {4194304, 16777216, 1048576, 16777216, 2097152, 3145728, 6291456, 8388608};
  static const int ws_sz[8] = {2097152,  2097152, 1048576,  1048576, 4194304, 2359296, 2359296, 4194304};

  int ord = 0;
  if (n_in == 16) {
    bool m0 = true, m1 = true, m2 = true, m3 = true;
    for (int i = 0; i < 8; ++i) {
      if (in_sizes[2 * i] != xs_sz[i] || in_sizes[2 * i + 1] != ws_sz[i]) m0 = false;
      if (in_sizes[i] != xs_sz[i]     || in_sizes[8 + i]    != ws_sz[i]) m1 = false;
      if (in_sizes[i] != ws_sz[i]     || in_sizes[8 + i]    != xs_sz[i]) m2 = false;
      if (in_sizes[2 * i] != ws_sz[i] || in_sizes[2 * i + 1] != xs_sz[i]) m3 = false;
    }
    ord = m0 ? 0 : (m1 ? 1 : (m2 ? 2 : (m3 ? 3 : 0)));
  }
  const float* Xs[8];
  const float* Ws[8];
  for (int i = 0; i < 8; ++i) {
    switch (ord) {
      case 0: Xs[i] = (const float*)d_in[2 * i];     Ws[i] = (const float*)d_in[2 * i + 1]; break;
      case 1: Xs[i] = (const float*)d_in[i];         Ws[i] = (const float*)d_in[8 + i];     break;
      case 2: Xs[i] = (const float*)d_in[8 + i];     Ws[i] = (const float*)d_in[i];         break;
      default:Xs[i] = (const float*)d_in[2 * i + 1]; Ws[i] = (const float*)d_in[2 * i];     break;
    }
  }

  size_t xsz[8], wsz[8], osz[8], oofs[8];
  size_t xtot = 0, wtot = 0, ocum = 0;
  for (int i = 0; i < 8; ++i) {
    xsz[i] = (size_t)Ms[i] * Ks[i];
    wsz[i] = (size_t)Ns[i] * Ks[i];
    osz[i] = (size_t)Ms[i] * Ns[i];
    oofs[i] = ocum; ocum += osz[i];
    xtot += xsz[i]; wtot += wsz[i];
  }
  float* out = (float*)d_out;
  size_t need_all = (xtot + wtot) * 2;   // bytes

  // overlap guard: ws must not alias out or any input
  auto ovl = [](const void* a, size_t an, const void* b, size_t bn) {
    const char* pa = (const char*)a; const char* pb = (const char*)b;
    return pa < pb + bn && pb < pa + an;
  };
  bool bad_ws = (ws_size < need_all) ||
                ovl(d_ws, need_all, d_out, (size_t)out_size * 4);
  for (int i = 0; i < n_in && !bad_ws; ++i)
    bad_ws = ovl(d_ws, need_all, d_in[i], (size_t)in_sizes[i] * 4);

  if (bad_ws) {
    // distinctive slow-pass path: signals ws aliasing / too-small
    for (int g = 0; g < 8; ++g) {
      long MN = (long)Ms[g] * Ns[g];
      hipLaunchKernelGGL(naive_gemm_f32, dim3((int)((MN + 255) / 256)), dim3(256), 0, stream,
                         Xs[g], Ws[g], out + oofs[g], MN, Ns[g], Ks[g]);
    }
    return;
  }

  u16* ws = (u16*)d_ws;
  u16* xdst[8]; u16* wdst[8];
  size_t off = 0;
  for (int i = 0; i < 8; ++i) { xdst[i] = ws + off; off += xsz[i]; }
  for (int i = 0; i < 8; ++i) { wdst[i] = ws + off; off += wsz[i]; }

  // 1) table cvt for ALL buffers (under test)
  CvtTable ct{};
  int cb = 0;
  for (int i = 0; i < 16; ++i) {
    const float* s = (i < 8) ? Xs[i] : Ws[i - 8];
    u16* d        = (i < 8) ? xdst[i] : wdst[i - 8];
    size_t n      = (i < 8) ? xsz[i] : wsz[i - 8];
    ct.src[i] = s; ct.dst[i] = d; ct.blk_start[i] = cb;
    cb += (int)(n / 1024);
  }
  ct.nbuf = 16;
  hipLaunchKernelGGL(cvt_f32_to_bf16, dim3(cb), dim3(256), 0, stream, ct);

  // 2) scalar cvt OVERWRITES groups 0 and 4 (trusted data for probes 0 and 4)
  hipLaunchKernelGGL(cvt_scalar, dim3((int)(xsz[0] / 256)), dim3(256), 0, stream, Xs[0], xdst[0], (long)xsz[0]);
  hipLaunchKernelGGL(cvt_scalar, dim3((int)(wsz[0] / 256)), dim3(256), 0, stream, Ws[0], wdst[0], (long)wsz[0]);
  hipLaunchKernelGGL(cvt_scalar, dim3((int)(xsz[4] / 256)), dim3(256), 0, stream, Xs[4], xdst[4], (long)xsz[4]);
  hipLaunchKernelGGL(cvt_scalar, dim3((int)(wsz[4] / 256)), dim3(256), 0, stream, Ws[4], wdst[4], (long)wsz[4]);

  // out0: scalar-cvt'd ws -> naive bf16 (probes ws mechanism)
  {
    long MN = (long)Ms[0] * Ns[0];
    hipLaunchKernelGGL(naive_gemm_bf16, dim3((int)((MN + 255) / 256)), dim3(256), 0, stream,
                       xdst[0], wdst[0], out + oofs[0], MN, Ns[0], Ks[0]);
  }
  // out1: table-cvt'd ws -> naive bf16 (exact round-3 failing probe)
  {
    long MN = (long)Ms[1] * Ns[1];
    hipLaunchKernelGGL(naive_gemm_bf16, dim3((int)((MN + 255) / 256)), dim3(256), 0, stream,
                       xdst[1], wdst[1], out + oofs[1], MN, Ns[1], Ks[1]);
  }
  // out2: fp32 control (mapping re-confirm)
  {
    long MN = (long)Ms[2] * Ns[2];
    hipLaunchKernelGGL(naive_gemm_f32, dim3((int)((MN + 255) / 256)), dim3(256), 0, stream,
                       Xs[2], Ws[2], out + oofs[2], MN, Ns[2], Ks[2]);
  }
  // out3: on-the-fly bf16, no ws (numerics control)
  {
    long MN = (long)Ms[3] * Ns[3];
    hipLaunchKernelGGL(naive_gemm_rt_bf16, dim3((int)((MN + 255) / 256)), dim3(256), 0, stream,
                       Xs[3], Ws[3], out + oofs[3], MN, Ns[3], Ks[3]);
  }
  // out4: MFMA kernel, single group, scalar-cvt'd (trusted) data
  {
    GemmTable gt{};
    gt.A[0] = xdst[4]; gt.B[0] = wdst[4]; gt.C[0] = out + oofs[4];
    gt.N[0] = Ns[4]; gt.K[0] = Ks[4]; gt.tstart[0] = 0;
    gt.ngroups = 1; gt.total = (Ms[4] >> 7) * (Ns[4] >> 7);
    hipLaunchKernelGGL(gemm_bf16_grouped, dim3(gt.total), dim3(256), 0, stream, gt);
  }
  // out5-7: MFMA grouped, table-cvt'd data
  {
    GemmTable gt{};
    int tiles = 0;
    for (int g = 5; g < 8; ++g) {
      int s = g - 5;
      gt.A[s] = xdst[g]; gt.B[s] = wdst[g]; gt.C[s] = out + oofs[g];
      gt.N[s] = Ns[g]; gt.K[s] = Ks[g];
      gt.tstart[s] = tiles;
      tiles += (Ms[g] >> 7) * (Ns[g] >> 7);
    }
    gt.ngroups = 3; gt.total = tiles;
    hipLaunchKernelGGL(gemm_bf16_grouped, dim3(tiles), dim3(256), 0, stream, gt);
  }
}

// Round 5
// 450.515 us; speedup vs baseline: 362.6522x; 362.6522x over previous
//
#include <hip/hip_runtime.h>
#include <hip/hip_bf16.h>

typedef unsigned short u16;
typedef unsigned int   u32;
typedef float  f32x4  __attribute__((ext_vector_type(4)));
typedef __bf16 bf16x8 __attribute__((ext_vector_type(8)));
typedef unsigned short u16x4 __attribute__((ext_vector_type(4)));

#define AS1(p) ((const __attribute__((address_space(1))) unsigned int*)(p))
#define AS3(p) ((__attribute__((address_space(3))) unsigned int*)(p))

__device__ __forceinline__ u16 rne_bf16(float f) {
  u32 u = __builtin_bit_cast(u32, f);
  return (u16)((u + 0x7fffu + ((u >> 16) & 1u)) >> 16);
}

// ---------------------------------------------------------------------------
// table-driven fp32 -> bf16 (validated r4): 1024 elems/block, f32x4 loads
// ---------------------------------------------------------------------------
struct CvtTable {
  const float* src[16];
  u16*         dst[16];
  int blk_start[16];
  int nbuf;
};

__global__ __launch_bounds__(256) void cvt_f32_to_bf16(CvtTable t) {
  int blk = blockIdx.x;
  int b = 0;
#pragma unroll
  for (int i = 1; i < 16; ++i)
    if (i < t.nbuf && blk >= t.blk_start[i]) b = i;
  long off4 = (long)(blk - t.blk_start[b]) * 256 + threadIdx.x;
  f32x4 v = ((const f32x4*)t.src[b])[off4];
  u16x4 o;
#pragma unroll
  for (int j = 0; j < 4; ++j) o[j] = rne_bf16(v[j]);
  ((u16x4*)t.dst[b])[off4] = o;
}

// ---------------------------------------------------------------------------
// Grouped bf16 GEMM, m97 structure (validated r4 via reg-staged twin; r1==r2
// certifies global_load_lds staging): 128x128 tile, BK=32, 4 waves (2x2),
// mfma_f32_16x16x32_bf16, global_load_lds width=16, 2-barrier K-loop.
// A: [M][K] bf16, B: [N][K] bf16 (w layout), C: [M][N] f32.
// ---------------------------------------------------------------------------
struct GemmTable {
  const u16* A[8];
  const u16* B[8];
  float*     C[8];
  int N[8], K[8];
  int tstart[8];
  int ngroups;
  int total;
};

__global__ __launch_bounds__(256) void gemm_bf16_grouped(GemmTable t) {
  // bijective XCD-aware swizzle (m204)
  int nwg  = t.total;
  int orig = blockIdx.x;
  int q = nwg >> 3, r = nwg & 7;
  int xcd = orig & 7, idx = orig >> 3;
  int wgid = (xcd < r ? xcd * (q + 1) : r * (q + 1) + (xcd - r) * q) + idx;

  int g = 0;
#pragma unroll
  for (int i = 1; i < 8; ++i)
    if (i < t.ngroups && wgid >= t.tstart[i]) g = i;

  const int K = t.K[g];
  const int N = t.N[g];
  int local = wgid - t.tstart[g];
  int ntn = N >> 7;
  int bm = local / ntn;
  int bn = local - bm * ntn;

  __shared__ u16 lsA[128 * 32];
  __shared__ u16 lsB[128 * 32];

  const int tid  = threadIdx.x;
  const int wid  = tid >> 6;
  const int lane = tid & 63;
  const int wr = wid >> 1, wc = wid & 1;

  // staging chunk c = wid*2+j covers tile elems [(c*64+lane)*8, +8)
  const int e0 = ((wid * 2 + 0) * 64 + lane) * 8;
  const int e1 = ((wid * 2 + 1) * 64 + lane) * 8;
  const int r0 = e0 >> 5, c0 = e0 & 31;
  const int r1 = e1 >> 5, c1 = e1 & 31;

  const u16* a0 = t.A[g] + (size_t)(bm * 128 + r0) * K + c0;
  const u16* a1 = t.A[g] + (size_t)(bm * 128 + r1) * K + c1;
  const u16* b0 = t.B[g] + (size_t)(bn * 128 + r0) * K + c0;
  const u16* b1 = t.B[g] + (size_t)(bn * 128 + r1) * K + c1;

  u16* lA0 = &lsA[(wid * 2 + 0) * 512];   // wave-uniform LDS bases (m104 rule)
  u16* lA1 = &lsA[(wid * 2 + 1) * 512];
  u16* lB0 = &lsB[(wid * 2 + 0) * 512];
  u16* lB1 = &lsB[(wid * 2 + 1) * 512];

  f32x4 acc[4][4];
#pragma unroll
  for (int i = 0; i < 4; ++i)
#pragma unroll
    for (int j = 0; j < 4; ++j)
      acc[i][j] = (f32x4){0.f, 0.f, 0.f, 0.f};

  const int arow = wr * 64 + (lane & 15);
  const int brow = wc * 64 + (lane & 15);
  const int kcol = (lane >> 4) * 8;

  for (int k0 = 0; k0 < K; k0 += 32) {
    __builtin_amdgcn_global_load_lds(AS1(a0 + k0), AS3(lA0), 16, 0, 0);
    __builtin_amdgcn_global_load_lds(AS1(a1 + k0), AS3(lA1), 16, 0, 0);
    __builtin_amdgcn_global_load_lds(AS1(b0 + k0), AS3(lB0), 16, 0, 0);
    __builtin_amdgcn_global_load_lds(AS1(b1 + k0), AS3(lB1), 16, 0, 0);
    __syncthreads();   // compiler drains vmcnt before barrier

    bf16x8 af[4], bfr[4];
#pragma unroll
    for (int i = 0; i < 4; ++i)
      af[i] = *(const bf16x8*)&lsA[(arow + i * 16) * 32 + kcol];
#pragma unroll
    for (int j = 0; j < 4; ++j)
      bfr[j] = *(const bf16x8*)&lsB[(brow + j * 16) * 32 + kcol];

#pragma unroll
    for (int i = 0; i < 4; ++i)
#pragma unroll
      for (int j = 0; j < 4; ++j)
        acc[i][j] = __builtin_amdgcn_mfma_f32_16x16x32_bf16(af[i], bfr[j], acc[i][j], 0, 0, 0);
    __syncthreads();
  }

  // C/D layout (m89/m91): col = lane&15, row = (lane>>4)*4 + reg
  float* Cp = t.C[g];
  const int crow = bm * 128 + wr * 64 + (lane >> 4) * 4;
  const int ccol = bn * 128 + wc * 64 + (lane & 15);
#pragma unroll
  for (int i = 0; i < 4; ++i)
#pragma unroll
    for (int j = 0; j < 4; ++j)
#pragma unroll
      for (int rr = 0; rr < 4; ++rr)
        Cp[(size_t)(crow + i * 16 + rr) * N + ccol + j * 16] = acc[i][j][rr];
}

// ---------------------------------------------------------------------------
// naive fp32 fallback (only if ws unusable)
// ---------------------------------------------------------------------------
__global__ __launch_bounds__(256) void naive_gemm_f32(const float* __restrict__ X,
                                                      const float* __restrict__ W,
                                                      float* __restrict__ C,
                                                      long MN, int N, int K) {
  long i = (long)blockIdx.x * 256 + threadIdx.x;
  if (i >= MN) return;
  int m = (int)(i / N), n = (int)(i - (long)m * N);
  const float* x = X + (size_t)m * K;
  const float* w = W + (size_t)n * K;
  float s = 0.f;
  for (int k = 0; k < K; ++k) s += x[k] * w[k];
  C[i] = s;
}

// ---------------------------------------------------------------------------
extern "C" void kernel_launch(void* const* d_in, const int* in_sizes, int n_in,
                              void* d_out, int out_size, void* d_ws, size_t ws_size,
                              hipStream_t stream) {
  static const int Ms[8] = {4096, 8192, 2048, 16384, 1024, 4096, 2048, 8192};
  static const int Ks[8] = {1024, 2048,  512,  1024, 2048,  768, 3072, 1024};
  static const int Ns[8] = {2048, 1024, 2048,  1024, 2048, 3072,  768, 4096};
  static const int xs_sz[8] = {4194304, 16777216, 1048576, 16777216, 2097152, 3145728, 6291456, 8388608};
  static const int ws_sz[8] = {2097152,  2097152, 1048576,  1048576, 4194304, 2359296, 2359296, 4194304};

  // robust input-order detection (validated r3/r4): full 16-elem signature
  int ord = 0;
  if (n_in == 16) {
    bool m0 = true, m1 = true, m2 = true, m3 = true;
    for (int i = 0; i < 8; ++i) {
      if (in_sizes[2 * i] != xs_sz[i] || in_sizes[2 * i + 1] != ws_sz[i]) m0 = false;
      if (in_sizes[i] != xs_sz[i]     || in_sizes[8 + i]    != ws_sz[i]) m1 = false;
      if (in_sizes[i] != ws_sz[i]     || in_sizes[8 + i]    != xs_sz[i]) m2 = false;
      if (in_sizes[2 * i] != ws_sz[i] || in_sizes[2 * i + 1] != xs_sz[i]) m3 = false;
    }
    ord = m0 ? 0 : (m1 ? 1 : (m2 ? 2 : (m3 ? 3 : 0)));
  }
  const float* Xs[8];
  const float* Ws[8];
  for (int i = 0; i < 8; ++i) {
    switch (ord) {
      case 0: Xs[i] = (const float*)d_in[2 * i];     Ws[i] = (const float*)d_in[2 * i + 1]; break;
      case 1: Xs[i] = (const float*)d_in[i];         Ws[i] = (const float*)d_in[8 + i];     break;
      case 2: Xs[i] = (const float*)d_in[8 + i];     Ws[i] = (const float*)d_in[i];         break;
      default:Xs[i] = (const float*)d_in[2 * i + 1]; Ws[i] = (const float*)d_in[2 * i];     break;
    }
  }

  size_t xsz[8], wsz[8], osz[8], oofs[8];
  size_t xtot = 0, wtot = 0, ocum = 0;
  for (int i = 0; i < 8; ++i) {
    xsz[i] = (size_t)Ms[i] * Ks[i];
    wsz[i] = (size_t)Ns[i] * Ks[i];
    osz[i] = (size_t)Ms[i] * Ns[i];
    oofs[i] = ocum; ocum += osz[i];
    xtot += xsz[i]; wtot += wsz[i];
  }
  float* out = (float*)d_out;
  size_t need_all = (xtot + wtot) * 2;   // bytes

  // ws sanity: size + no aliasing with out / inputs
  auto ovl = [](const void* a, size_t an, const void* b, size_t bn) {
    const char* pa = (const char*)a; const char* pb = (const char*)b;
    return pa < pb + bn && pb < pa + an;
  };
  bool bad_ws = (ws_size < need_all) ||
                ovl(d_ws, need_all, d_out, (size_t)out_size * 4);
  for (int i = 0; i < n_in && !bad_ws; ++i)
    bad_ws = ovl(d_ws, need_all, d_in[i], (size_t)in_sizes[i] * 4);

  if (bad_ws) {
    for (int g = 0; g < 8; ++g) {
      long MN = (long)Ms[g] * Ns[g];
      hipLaunchKernelGGL(naive_gemm_f32, dim3((int)((MN + 255) / 256)), dim3(256), 0, stream,
                         Xs[g], Ws[g], out + oofs[g], MN, Ns[g], Ks[g]);
    }
    return;
  }

  u16* ws = (u16*)d_ws;
  u16* xdst[8]; u16* wdst[8];
  size_t off = 0;
  for (int i = 0; i < 8; ++i) { xdst[i] = ws + off; off += xsz[i]; }
  for (int i = 0; i < 8; ++i) { wdst[i] = ws + off; off += wsz[i]; }

  // one conversion launch for all 16 buffers
  CvtTable ct{};
  int cb = 0;
  for (int i = 0; i < 16; ++i) {
    const float* s = (i < 8) ? Xs[i] : Ws[i - 8];
    u16* d        = (i < 8) ? xdst[i] : wdst[i - 8];
    size_t n      = (i < 8) ? xsz[i] : wsz[i - 8];
    ct.src[i] = s; ct.dst[i] = d; ct.blk_start[i] = cb;
    cb += (int)(n / 1024);
  }
  ct.nbuf = 16;
  hipLaunchKernelGGL(cvt_f32_to_bf16, dim3(cb), dim3(256), 0, stream, ct);

  // one grouped GEMM launch over all 8 groups (5344 tiles)
  GemmTable gt{};
  int tiles = 0;
  for (int i = 0; i < 8; ++i) {
    gt.A[i] = xdst[i]; gt.B[i] = wdst[i]; gt.C[i] = out + oofs[i];
    gt.N[i] = Ns[i]; gt.K[i] = Ks[i];
    gt.tstart[i] = tiles;
    tiles += (Ms[i] >> 7) * (Ns[i] >> 7);
  }
  gt.ngroups = 8; gt.total = tiles;
  hipLaunchKernelGGL(gemm_bf16_grouped, dim3(tiles), dim3(256), 0, stream, gt);
}